// Round 10
// baseline (28.912 us; speedup 1.0000x reference)
//
#include <hip/hip_runtime.h>
#include <hip/hip_bf16.h>
#include <cstddef>

typedef __attribute__((ext_vector_type(8))) short bf16x8;
typedef __attribute__((ext_vector_type(4))) float f32x4;
typedef __attribute__((ext_vector_type(2))) unsigned int u32x2;

#define NB 4
#define CIN 64
#define COUT 64
#define HH 128
#define WW 128
#define TAPS 9
#define STRD 82      // dwords per sCor row (stride 18 mod 32 banks -> conflict-free)

__device__ __forceinline__ unsigned short f2bf(float f) {
    union { float f; unsigned u; } v; v.f = f;
    unsigned u = v.u + 0x7FFFu + ((v.u >> 16) & 1u);   // RNE
    return (unsigned short)(u >> 16);
}

// Coalesced frag layout (proven R9): wBv[((wv*20 + chunk*5 + step)*64 + lane)*8 + e]
// lane = g*16 + l15, o = wv*16 + l15, kk = step*32 + g*8 + e (tap=kk>>4, cl=kk&15)
__global__ void prep_weight(const float* __restrict__ w, unsigned short* __restrict__ wBv) {
    int idx = blockIdx.x * blockDim.x + threadIdx.x;
    if (idx >= 40960) return;
    int e    = idx & 7;
    int lane = (idx >> 3) & 63;
    int fid  = idx >> 9;               // wv*20 + chunk*5 + step
    int wv   = fid / 20;
    int rem  = fid - wv * 20;
    int chunk = rem / 5;
    int step  = rem - chunk * 5;
    int l15 = lane & 15, g = lane >> 4;
    int o  = wv * 16 + l15;
    int kk = step * 32 + g * 8 + e;
    unsigned short v = 0;
    if (kk < 144) {
        int tap = kk >> 4;
        int cl  = kk & 15;
        v = f2bf(w[(o * CIN + chunk * 16 + cl) * TAPS + tap]);
    }
    wBv[idx] = v;
}

__launch_bounds__(256, 8)
__global__ void pac_conv(const float* __restrict__ x, const float* __restrict__ Kp,
                         const unsigned short* __restrict__ wBv,
                         const float* __restrict__ bias,
                         float* __restrict__ out) {
    __shared__ unsigned int sCor[32][STRD];   // 10496 B -> 8 blocks/CU (grid-capped)

    // XCD-chunked bijective swizzle (2048 % 8 == 0): each XCD gets 256
    // consecutive logical blocks = one n, 64 adjacent h -> ~2.3 MB L2 slice.
    const int blk0 = blockIdx.x;
    const int blk  = ((blk0 & 7) << 8) | (blk0 >> 3);

    const int w0 = (blk & 3) * 32;
    const int h  = (blk >> 2) & (HH - 1);
    const int n  = blk >> 9;

    const int t    = threadIdx.x;
    const int lane = t & 63;
    const int wv   = __builtin_amdgcn_readfirstlane(t >> 6);
    const int px   = lane & 31;          // pixel within 32-px segment
    const int cpair = t >> 5;            // 0..7 -> channels 2*cpair, 2*cpair+1 (chunk-local)

    // per-pixel adapting kernel -> registers
    float kreg[TAPS];
    float ks = 0.f;
    const float* kp = Kp + ((size_t)n * TAPS * HH + h) * WW + w0 + px;
    #pragma unroll
    for (int tap = 0; tap < TAPS; ++tap) {
        kreg[tap] = kp[(size_t)tap * HH * WW];
        ks += kreg[tap];
    }
    const float inv = 1.0f / ks;

    // zero K-pad dwords 72..79 (kl 144..159): 32 rows x 8 = 256, one per thread
    sCor[t >> 3][72 + (t & 7)] = 0u;

    // w-edges: only true image edges need masking; segment seams are interior
    const bool mL = (w0 == 0)  && (px == 0);
    const bool mR = (w0 == 96) && (px == 31);
    const unsigned voffL = (mL ? 1u : (unsigned)px) * 4u;                  // l=0
    const unsigned voffC = ((unsigned)px + 1u) * 4u;                       // l=1
    const unsigned voffR = (mR ? (unsigned)px : (unsigned)px + 2u) * 4u;   // l=2

    const int l15 = lane & 15;
    const int g   = lane >> 4;
    const float bval = bias[wv * 16 + l15];

    f32x4 acc[2];
    acc[0] = (f32x4){0.f, 0.f, 0.f, 0.f};
    acc[1] = (f32x4){0.f, 0.f, 0.f, 0.f};

    #pragma unroll
    for (int chunk = 0; chunk < 4; ++chunk) {
        const int c0 = chunk * 16 + cpair * 2;
        const float* xb = x + (size_t)(n * CIN + c0) * (HH * WW) + w0 - 1;  // -1 bias

        // ---- stage 2 channels: per-j 9 loads (small live set), dom, corrected ----
        unsigned int cor[TAPS];
        float cprev[TAPS];
        #pragma unroll
        for (int j = 0; j < 2; ++j) {
            float xv[TAPS];
            #pragma unroll
            for (int k = 0; k < 3; ++k) {
                const int hh2 = h + k - 1;
                const bool hok = (unsigned)hh2 < (unsigned)HH;
                const int hc = hok ? hh2 : (hh2 < 0 ? 0 : HH - 1);
                const float* p = xb + (size_t)j * (HH * WW) + (size_t)hc * WW;
                float vL = *(const float*)((const char*)p + voffL);
                float vC = *(const float*)((const char*)p + voffC);
                float vR = *(const float*)((const char*)p + voffR);
                xv[k * 3 + 0] = (hok && !mL) ? vL : 0.f;
                xv[k * 3 + 1] = hok ? vC : 0.f;
                xv[k * 3 + 2] = (hok && !mR) ? vR : 0.f;
            }
            float s = 0.f;
            #pragma unroll
            for (int tap = 0; tap < TAPS; ++tap) s = fmaf(xv[tap], kreg[tap], s);
            const float d = s * inv;
            if (j == 0) {
                #pragma unroll
                for (int tap = 0; tap < TAPS; ++tap)
                    cprev[tap] = fmaf(kreg[tap], xv[tap] - d, d);
            } else {
                #pragma unroll
                for (int tap = 0; tap < TAPS; ++tap) {
                    float cc = fmaf(kreg[tap], xv[tap] - d, d);
                    union { __hip_bfloat162 h2; unsigned int u; } pk;
                    pk.h2 = __float22bfloat162_rn(make_float2(cprev[tap], cc));
                    cor[tap] = pk.u;
                }
            }
        }

        if (chunk) __syncthreads();          // previous MFMA readers done
        #pragma unroll
        for (int tap = 0; tap < TAPS; ++tap)
            sCor[px][tap * 8 + cpair] = cor[tap];
        __syncthreads();

        // ---- MFMA: wave owns 16 outputs x 32 px; coalesced B-frag loads ----
        const unsigned short* wfb =
            wBv + (((size_t)(wv * 20 + chunk * 5) << 6) + lane) * 8;   // +step*512
        #pragma unroll
        for (int step = 0; step < 5; ++step) {
            bf16x8 bfrag = *reinterpret_cast<const bf16x8*>(wfb + (step << 9));
            #pragma unroll
            for (int pt = 0; pt < 2; ++pt) {
                const unsigned int* ap = &sCor[pt * 16 + l15][step * 16 + g * 4];
                u32x2 alo = *reinterpret_cast<const u32x2*>(ap);
                u32x2 ahi = *reinterpret_cast<const u32x2*>(ap + 2);
                union { u32x2 p[2]; bf16x8 f; } af;
                af.p[0] = alo; af.p[1] = ahi;
                acc[pt] = __builtin_amdgcn_mfma_f32_16x16x32_bf16(af.f, bfrag, acc[pt], 0, 0, 0);
            }
        }
    }

    // epilogue: direct float4 stores (rows = px = pt*16 + g*4 + r)
    const int o = wv * 16 + l15;
    float* op = out + (((size_t)n * COUT + o) * HH + h) * WW + w0 + g * 4;
    #pragma unroll
    for (int pt = 0; pt < 2; ++pt) {
        f32x4 v = acc[pt];
        #pragma unroll
        for (int r = 0; r < 4; ++r) v[r] += bval;
        *reinterpret_cast<f32x4*>(op + pt * 16) = v;
    }
}

extern "C" void kernel_launch(void* const* d_in, const int* in_sizes, int n_in,
                              void* d_out, int out_size, void* d_ws, size_t ws_size,
                              hipStream_t stream) {
    const float* x    = (const float*)d_in[0];
    const float* Kp   = (const float*)d_in[1];
    const float* wgt  = (const float*)d_in[2];
    const float* bias = (const float*)d_in[3];
    float* out = (float*)d_out;
    unsigned short* wBv = (unsigned short*)d_ws;             // 81920 B

    prep_weight<<<160, 256, 0, stream>>>(wgt, wBv);

    pac_conv<<<NB * HH * (WW / 32), 256, 0, stream>>>(x, Kp, wBv, bias, out);
}